// Round 1
// baseline (1254.999 us; speedup 1.0000x reference)
//
#include <hip/hip_runtime.h>
#include <math.h>

// Problem constants (from reference):
#define B_ 4096
#define T_ 64
#define E_ 256
#define H_ 64
#define G_ 256   // 4*H

// ---------------------------------------------------------------------------
// Prep: transpose weights for coalesced access, fuse biases.
//   WihT[e][g] = W_ih[g][e]   (256x256)
//   WhhT[k][g] = W_hh[g][k]   (64x256)
//   bias[g]    = b_ih[g] + b_hh[g]
// ---------------------------------------------------------------------------
__global__ void prep_kernel(const float* __restrict__ W_ih,
                            const float* __restrict__ W_hh,
                            const float* __restrict__ b_ih,
                            const float* __restrict__ b_hh,
                            float* __restrict__ WihT,
                            float* __restrict__ WhhT,
                            float* __restrict__ bias) {
    int tid = blockIdx.x * blockDim.x + threadIdx.x;
    int stride = gridDim.x * blockDim.x;
    for (int i = tid; i < G_ * E_; i += stride) {
        int g = i >> 8;        // /256
        int e = i & 255;
        WihT[e * G_ + g] = W_ih[g * E_ + e];
    }
    for (int i = tid; i < G_ * H_; i += stride) {
        int g = i >> 6;        // /64
        int k = i & 63;
        WhhT[k * G_ + g] = W_hh[g * H_ + k];
    }
    for (int i = tid; i < G_; i += stride) {
        bias[i] = b_ih[i] + b_hh[i];
    }
}

__device__ __forceinline__ float sigmoidf_(float x) {
    return 1.0f / (1.0f + __expf(-x));
}

#define FMA4(ACC, S, W) \
    ACC.x += (S) * (W).x; ACC.y += (S) * (W).y; \
    ACC.z += (S) * (W).z; ACC.w += (S) * (W).w;

// ---------------------------------------------------------------------------
// Fused LSTM: each block owns BB=16 batch rows for all T=64 steps.
// 512 threads = 8 waves.
// GEMM mapping: thread -> 4 consecutive gates (g4 = (tid&63)*4), 2 rows
//               (row group rg = tid>>6 owns rows 2*rg, 2*rg+1).
// Gate mapping: thread -> hidden j = tid&63, rows rr = tid>>6 and rr+8.
// ---------------------------------------------------------------------------
#define BB 16
#define THREADS 512

__global__ __launch_bounds__(THREADS, 1)
void lstm_fused_kernel(const int* __restrict__ x,
                       const float* __restrict__ emb_table,
                       const float* __restrict__ WihT,
                       const float* __restrict__ WhhT,
                       const float* __restrict__ bias,
                       float* __restrict__ out) {
    __shared__ float s_emb[BB][E_];   // 16 KB
    __shared__ float s_G[BB][G_];     // 16 KB
    __shared__ float s_h[BB][H_];     // 4 KB
    __shared__ int   s_idx[BB][T_];   // 4 KB

    const int tid = threadIdx.x;
    const int r0  = blockIdx.x * BB;

    // GEMM-phase mapping
    const int g4 = (tid & 63) << 2;   // gate quad base
    const int rg = tid >> 6;          // 0..7
    const int ra = rg * 2;
    const int rb = rg * 2 + 1;
    // Gate-phase mapping
    const int j  = tid & 63;
    const int rr = tid >> 6;          // rows rr and rr+8

    // Preload all indices for this block's rows; zero h state.
    for (int i = tid; i < BB * T_; i += THREADS) {
        (&s_idx[0][0])[i] = x[r0 * T_ + i];
    }
    for (int i = tid; i < BB * H_; i += THREADS) {
        (&s_h[0][0])[i] = 0.0f;
    }
    const float4 bias4 = *(const float4*)&bias[g4];
    __syncthreads();

    float c0 = 0.0f, c1 = 0.0f;   // cell state for rows rr, rr+8

    for (int t = 0; t < T_; ++t) {
        // ---- stage embedding tile: 16 rows x 256 floats = 1024 float4 ----
        {
            int f  = tid;                 // float4 id 0..511
            int r1 = f >> 6;
            int cc = (f & 63) << 2;
            int row = s_idx[r1][t];
            *(float4*)&s_emb[r1][cc] =
                *(const float4*)&emb_table[row * E_ + cc];
            int f2 = tid + THREADS;       // 512..1023
            int r2 = f2 >> 6;
            int c2 = (f2 & 63) << 2;
            int row2 = s_idx[r2][t];
            *(float4*)&s_emb[r2][c2] =
                *(const float4*)&emb_table[row2 * E_ + c2];
        }
        __syncthreads();   // B1: emb staged, previous gate-phase h writes visible

        // ---- G = emb @ WihT + h @ WhhT + bias ----
        float4 accA = bias4;
        float4 accB = bias4;

        #pragma unroll 4
        for (int e = 0; e < E_; e += 4) {
            const float4 w0 = *(const float4*)&WihT[(e + 0) * G_ + g4];
            const float4 w1 = *(const float4*)&WihT[(e + 1) * G_ + g4];
            const float4 w2 = *(const float4*)&WihT[(e + 2) * G_ + g4];
            const float4 w3 = *(const float4*)&WihT[(e + 3) * G_ + g4];
            const float4 ea = *(const float4*)&s_emb[ra][e];
            const float4 eb = *(const float4*)&s_emb[rb][e];
            FMA4(accA, ea.x, w0) FMA4(accA, ea.y, w1)
            FMA4(accA, ea.z, w2) FMA4(accA, ea.w, w3)
            FMA4(accB, eb.x, w0) FMA4(accB, eb.y, w1)
            FMA4(accB, eb.z, w2) FMA4(accB, eb.w, w3)
        }

        #pragma unroll 4
        for (int k = 0; k < H_; k += 4) {
            const float4 w0 = *(const float4*)&WhhT[(k + 0) * G_ + g4];
            const float4 w1 = *(const float4*)&WhhT[(k + 1) * G_ + g4];
            const float4 w2 = *(const float4*)&WhhT[(k + 2) * G_ + g4];
            const float4 w3 = *(const float4*)&WhhT[(k + 3) * G_ + g4];
            const float4 ha = *(const float4*)&s_h[ra][k];
            const float4 hb = *(const float4*)&s_h[rb][k];
            FMA4(accA, ha.x, w0) FMA4(accA, ha.y, w1)
            FMA4(accA, ha.z, w2) FMA4(accA, ha.w, w3)
            FMA4(accB, hb.x, w0) FMA4(accB, hb.y, w1)
            FMA4(accB, hb.z, w2) FMA4(accB, hb.w, w3)
        }

        *(float4*)&s_G[ra][g4] = accA;
        *(float4*)&s_G[rb][g4] = accB;
        __syncthreads();   // B2: G complete

        // ---- gate phase: rows rr and rr+8, hidden index j ----
        {
            float gi = s_G[rr][j];
            float gf = s_G[rr][64 + j];
            float gg = s_G[rr][128 + j];
            float go = s_G[rr][192 + j];
            float si = sigmoidf_(gi);
            float sf = sigmoidf_(gf);
            float so = sigmoidf_(go);
            c0 = sf * c0 + si * tanhf(gg);
            float h0v = so * tanhf(c0);
            s_h[rr][j] = h0v;

            const int r2 = rr + 8;
            float gi1 = s_G[r2][j];
            float gf1 = s_G[r2][64 + j];
            float gg1 = s_G[r2][128 + j];
            float go1 = s_G[r2][192 + j];
            float si1 = sigmoidf_(gi1);
            float sf1 = sigmoidf_(gf1);
            float so1 = sigmoidf_(go1);
            c1 = sf1 * c1 + si1 * tanhf(gg1);
            float h1v = so1 * tanhf(c1);
            s_h[r2][j] = h1v;

            if (t == T_ - 1) {
                out[(r0 + rr) * H_ + j] = h0v;
                out[(r0 + r2) * H_ + j] = h1v;
            }
        }
        // No trailing barrier needed: next iteration's B1 orders gate-phase
        // writes (s_h) before the next GEMM reads; emb staging touches only
        // s_emb/s_idx which nothing else is using at that point.
    }
}

// ---------------------------------------------------------------------------
extern "C" void kernel_launch(void* const* d_in, const int* in_sizes, int n_in,
                              void* d_out, int out_size, void* d_ws, size_t ws_size,
                              hipStream_t stream) {
    const int*   x          = (const int*)d_in[0];
    const float* emb_table  = (const float*)d_in[1];
    const float* W_ih       = (const float*)d_in[2];
    const float* W_hh       = (const float*)d_in[3];
    const float* b_ih       = (const float*)d_in[4];
    const float* b_hh       = (const float*)d_in[5];
    float*       out        = (float*)d_out;

    float* ws   = (float*)d_ws;
    float* WihT = ws;                       // 65536 floats
    float* WhhT = ws + 65536;               // 16384 floats
    float* bias = ws + 65536 + 16384;       // 256 floats

    prep_kernel<<<64, 256, 0, stream>>>(W_ih, W_hh, b_ih, b_hh, WihT, WhhT, bias);
    lstm_fused_kernel<<<B_ / BB, THREADS, 0, stream>>>(x, emb_table, WihT, WhhT, bias, out);
}

// Round 2
// 121.320 us; speedup vs baseline: 10.3445x; 10.3445x over previous
//
#include <hip/hip_runtime.h>
#include <math.h>

#define B_ 4096
#define T_ 64
#define E_ 256
#define H_ 64
#define G_ 256   // 4*H

typedef __attribute__((ext_vector_type(8))) short bf16x8;
typedef __attribute__((ext_vector_type(4))) float f32x4;

__device__ __forceinline__ short f2bf(float x) {
    // round-to-nearest-even f32 -> bf16 (no NaN inputs here)
    unsigned u = __float_as_uint(x);
    unsigned r = (u + 0x7FFFu + ((u >> 16) & 1u)) >> 16;
    return (short)r;
}
__device__ __forceinline__ float bf2f(short s) {
    return __uint_as_float(((unsigned)(unsigned short)s) << 16);
}
__device__ __forceinline__ float tanh_fast(float x) {
    float xc = fminf(fmaxf(x, -9.0f), 9.0f);
    float e = __expf(2.0f * xc);
    return (e - 1.0f) / (e + 1.0f);
}
__device__ __forceinline__ float sigmoid_fast(float x) {
    return 1.0f / (1.0f + __expf(-x));
}

// ---------------------------------------------------------------------------
// Prep: convert weights to bf16 (W_ih split hi+lo for precision), fuse biases.
// Layouts kept as original [g][k] row-major (that's what B-fragments want:
// 8 contiguous k for a fixed gate column g).
// ---------------------------------------------------------------------------
__global__ void prep_kernel(const float* __restrict__ W_ih,
                            const float* __restrict__ W_hh,
                            const float* __restrict__ b_ih,
                            const float* __restrict__ b_hh,
                            short* __restrict__ wih_hi,
                            short* __restrict__ wih_lo,
                            short* __restrict__ whh_b,
                            float* __restrict__ bias_f) {
    int tid = blockIdx.x * blockDim.x + threadIdx.x;
    int stride = gridDim.x * blockDim.x;
    for (int i = tid; i < G_ * E_; i += stride) {
        float w = W_ih[i];
        short hi = f2bf(w);
        wih_hi[i] = hi;
        wih_lo[i] = f2bf(w - bf2f(hi));
    }
    for (int i = tid; i < G_ * H_; i += stride) whh_b[i] = f2bf(W_hh[i]);
    for (int i = tid; i < G_; i += stride) bias_f[i] = b_ih[i] + b_hh[i];
}

// ---------------------------------------------------------------------------
// Fused MFMA LSTM. Block = 16 batch rows, 512 threads = 8 waves, grid 256.
// Wave w owns gate col-tiles 2w, 2w+1 (gates [32w,32w+32)); W_ih hi/lo and
// W_hh live in VGPRs as MFMA B-fragments for the whole kernel.
//
// MFMA 16x16x32 layouts (m89-verified family):
//   A: lane l supplies A[m = l&15][k = (l>>4)*8 + j], j=0..7
//   B: lane l supplies B[k = (l>>4)*8 + j][n = l&15]
//   D: lane l reg q  = D[m = (l>>4)*4 + q][n = l&15]
// ---------------------------------------------------------------------------
#define THREADS 512

__global__ __launch_bounds__(THREADS, 2)
void lstm_mfma_kernel(const int* __restrict__ x,
                      const float* __restrict__ emb,
                      const short* __restrict__ wih_hi,
                      const short* __restrict__ wih_lo,
                      const short* __restrict__ whh_b,
                      const float* __restrict__ bias_f,
                      float* __restrict__ out) {
    // XOR-swizzled LDS (byte ^= (row&7)<<4 for bf16 tiles; (r&12)<<2 for G)
    __shared__ __align__(16) short s_emb[16 * 256];  // 8 KB bf16
    __shared__ __align__(16) short s_h[16 * 64];     // 2 KB bf16
    __shared__ __align__(16) float s_G[16 * 256];    // 16 KB f32
    __shared__ int s_idx[16 * 64];                   // 4 KB

    const int tid  = threadIdx.x;
    const int lane = tid & 63;
    const int wave = tid >> 6;
    const int r0   = blockIdx.x * 16;

    // staging mapping: thread -> (row, 8-elem k segment)
    const int st_row = tid >> 5;          // 0..15
    const int st_kb  = (tid & 31) << 3;   // 0,8,..,248

    // fragment lane decomposition
    const int fcol = lane & 15;
    const int fk8  = (lane >> 4) << 3;    // 0,8,16,24
    const int gb   = wave * 32;

    // stage x indices (16 rows x 64 t), zero h
    s_idx[tid]       = x[r0 * T_ + tid];
    s_idx[tid + 512] = x[r0 * T_ + tid + 512];
    ((int*)s_h)[tid] = 0;
    __syncthreads();

    // ---- load W fragments into registers (once) ----
    bf16x8 wHI[2][8], wLO[2][8], wHH[2][2];
    float biasv[2];
    #pragma unroll
    for (int i = 0; i < 2; ++i) {
        const int g = gb + i * 16 + fcol;
        const short* ph = wih_hi + g * E_ + fk8;
        const short* pl = wih_lo + g * E_ + fk8;
        #pragma unroll
        for (int kc = 0; kc < 8; ++kc) {
            wHI[i][kc] = *(const bf16x8*)(ph + kc * 32);
            wLO[i][kc] = *(const bf16x8*)(pl + kc * 32);
        }
        const short* pq = whh_b + g * H_ + fk8;
        #pragma unroll
        for (int kc = 0; kc < 2; ++kc)
            wHH[i][kc] = *(const bf16x8*)(pq + kc * 32);
        biasv[i] = bias_f[g];
    }

    // prefetch emb for t=0
    float4 efA, efB;
    {
        int ridx = s_idx[st_row * T_ + 0];
        const float* p = emb + (size_t)ridx * E_ + st_kb;
        efA = *(const float4*)p;
        efB = *(const float4*)(p + 4);
    }

    float c0 = 0.0f, c1 = 0.0f;   // cell state: rows wave, wave+8

    for (int t = 0; t < T_; ++t) {
        // ---- A: convert prefetched emb -> bf16, store swizzled ----
        {
            bf16x8 pk;
            pk[0] = f2bf(efA.x); pk[1] = f2bf(efA.y);
            pk[2] = f2bf(efA.z); pk[3] = f2bf(efA.w);
            pk[4] = f2bf(efB.x); pk[5] = f2bf(efB.y);
            pk[6] = f2bf(efB.z); pk[7] = f2bf(efB.w);
            int byt = (st_row * 512 + st_kb * 2) ^ ((st_row & 7) << 4);
            *(bf16x8*)((char*)s_emb + byt) = pk;
        }
        __syncthreads();   // B1: emb(t) staged, h(t-1) visible

        // ---- B: prefetch emb for t+1 (latency hides under MFMA) ----
        if (t + 1 < T_) {
            int ridx = s_idx[st_row * T_ + t + 1];
            const float* p = emb + (size_t)ridx * E_ + st_kb;
            efA = *(const float4*)p;
            efB = *(const float4*)(p + 4);
        }

        // ---- C: MFMA  G = emb·(Whi+Wlo) + h·Whh + bias ----
        f32x4 acc[2][2];
        #pragma unroll
        for (int i = 0; i < 2; ++i) {
            acc[i][0] = (f32x4){biasv[i], biasv[i], biasv[i], biasv[i]};
            acc[i][1] = (f32x4){0.f, 0.f, 0.f, 0.f};
        }
        #pragma unroll
        for (int kc = 0; kc < 8; ++kc) {
            int byt = (fcol * 512 + (kc * 32 + fk8) * 2) ^ ((fcol & 7) << 4);
            bf16x8 a = *(const bf16x8*)((char*)s_emb + byt);
            acc[0][0] = __builtin_amdgcn_mfma_f32_16x16x32_bf16(a, wHI[0][kc], acc[0][0], 0, 0, 0);
            acc[1][0] = __builtin_amdgcn_mfma_f32_16x16x32_bf16(a, wHI[1][kc], acc[1][0], 0, 0, 0);
            acc[0][1] = __builtin_amdgcn_mfma_f32_16x16x32_bf16(a, wLO[0][kc], acc[0][1], 0, 0, 0);
            acc[1][1] = __builtin_amdgcn_mfma_f32_16x16x32_bf16(a, wLO[1][kc], acc[1][1], 0, 0, 0);
        }
        #pragma unroll
        for (int kc = 0; kc < 2; ++kc) {
            int byt = (fcol * 128 + (kc * 32 + fk8) * 2) ^ ((fcol & 7) << 4);
            bf16x8 ah = *(const bf16x8*)((char*)s_h + byt);
            acc[0][0] = __builtin_amdgcn_mfma_f32_16x16x32_bf16(ah, wHH[0][kc], acc[0][0], 0, 0, 0);
            acc[1][1] = __builtin_amdgcn_mfma_f32_16x16x32_bf16(ah, wHH[1][kc], acc[1][1], 0, 0, 0);
        }

        // ---- D: write G to LDS (row-swizzled to spread banks) ----
        #pragma unroll
        for (int i = 0; i < 2; ++i) {
            const int g = gb + i * 16 + fcol;
            #pragma unroll
            for (int q = 0; q < 4; ++q) {
                int r = ((lane >> 4) << 2) + q;
                int byt = (r * 1024 + g * 4) ^ ((r & 12) << 2);
                *(float*)((char*)s_G + byt) = acc[i][0][q] + acc[i][1][q];
            }
        }
        __syncthreads();   // B2: G complete

        // ---- E: gate math (wave w handles rows w and w+8, col j=lane) ----
        {
            const int j = lane;
            int r = wave;
            int base = r * 1024, sw = (r & 12) << 2;
            float gi = *(float*)((char*)s_G + ((base + (j      ) * 4) ^ sw));
            float gf = *(float*)((char*)s_G + ((base + (j +  64) * 4) ^ sw));
            float gg = *(float*)((char*)s_G + ((base + (j + 128) * 4) ^ sw));
            float go = *(float*)((char*)s_G + ((base + (j + 192) * 4) ^ sw));
            c0 = sigmoid_fast(gf) * c0 + sigmoid_fast(gi) * tanh_fast(gg);
            float h0 = sigmoid_fast(go) * tanh_fast(c0);
            *(short*)((char*)s_h + ((r * 128 + j * 2) ^ ((r & 7) << 4))) = f2bf(h0);

            r = wave + 8;
            base = r * 1024; sw = (r & 12) << 2;
            float gi1 = *(float*)((char*)s_G + ((base + (j      ) * 4) ^ sw));
            float gf1 = *(float*)((char*)s_G + ((base + (j +  64) * 4) ^ sw));
            float gg1 = *(float*)((char*)s_G + ((base + (j + 128) * 4) ^ sw));
            float go1 = *(float*)((char*)s_G + ((base + (j + 192) * 4) ^ sw));
            c1 = sigmoid_fast(gf1) * c1 + sigmoid_fast(gi1) * tanh_fast(gg1);
            float h1 = sigmoid_fast(go1) * tanh_fast(c1);
            *(short*)((char*)s_h + ((r * 128 + j * 2) ^ ((r & 7) << 4))) = f2bf(h1);

            if (t == T_ - 1) {
                out[(r0 + wave) * H_ + j]     = h0;
                out[(r0 + wave + 8) * H_ + j] = h1;
            }
        }
        // next iteration's B1 orders s_h writes before MFMA reads; B2 ordered
        // s_emb reads before next staging overwrite.
    }
}

// ---------------------------------------------------------------------------
extern "C" void kernel_launch(void* const* d_in, const int* in_sizes, int n_in,
                              void* d_out, int out_size, void* d_ws, size_t ws_size,
                              hipStream_t stream) {
    const int*   x         = (const int*)d_in[0];
    const float* emb_table = (const float*)d_in[1];
    const float* W_ih      = (const float*)d_in[2];
    const float* W_hh      = (const float*)d_in[3];
    const float* b_ih      = (const float*)d_in[4];
    const float* b_hh      = (const float*)d_in[5];
    float*       out       = (float*)d_out;

    short* wih_hi = (short*)d_ws;            // 65536 shorts (128 KB)
    short* wih_lo = wih_hi + 65536;          // 65536 shorts (128 KB)
    short* whh_b  = wih_lo + 65536;          // 16384 shorts (32 KB)
    float* bias_f = (float*)(whh_b + 16384); // 256 floats (1 KB)

    prep_kernel<<<64, 256, 0, stream>>>(W_ih, W_hh, b_ih, b_hh,
                                        wih_hi, wih_lo, whh_b, bias_f);
    lstm_mfma_kernel<<<B_ / 16, THREADS, 0, stream>>>(x, emb_table,
                                                      wih_hi, wih_lo, whh_b, bias_f,
                                                      out);
}

// Round 3
// 112.416 us; speedup vs baseline: 11.1639x; 1.0792x over previous
//
#include <hip/hip_runtime.h>
#include <math.h>

#define B_ 4096
#define T_ 64
#define E_ 256
#define H_ 64
#define G_ 256
#define THREADS 512

typedef __attribute__((ext_vector_type(8))) short bf16x8;
typedef __attribute__((ext_vector_type(4))) short bf16x4;
typedef __attribute__((ext_vector_type(4))) float f32x4;

__device__ __forceinline__ short f2bf(float x) {
    // round-to-nearest-even f32 -> bf16
    unsigned u = __float_as_uint(x);
    return (short)((u + 0x7FFFu + ((u >> 16) & 1u)) >> 16);
}
__device__ __forceinline__ float sigm(float x) {
    return 1.0f / (1.0f + __expf(-x));
}
__device__ __forceinline__ float tanh_(float x) {
    // 1 - 2/(1+e^{2x}); handles +-inf correctly, no clamp needed
    return 1.0f - 2.0f / (1.0f + __expf(2.0f * x));
}

// ---------------------------------------------------------------------------
// Prep: bf16 weights (row-major [g][k], B-fragment friendly), fused bias.
// ---------------------------------------------------------------------------
__global__ void prep_kernel(const float* __restrict__ W_ih,
                            const float* __restrict__ W_hh,
                            const float* __restrict__ b_ih,
                            const float* __restrict__ b_hh,
                            short* __restrict__ wih_b,
                            short* __restrict__ whh_b,
                            float* __restrict__ bias_f) {
    int tid = blockIdx.x * blockDim.x + threadIdx.x;
    int stride = gridDim.x * blockDim.x;
    for (int i = tid; i < G_ * E_; i += stride) wih_b[i] = f2bf(W_ih[i]);
    for (int i = tid; i < G_ * H_; i += stride) whh_b[i] = f2bf(W_hh[i]);
    for (int i = tid; i < G_; i += stride) bias_f[i] = b_ih[i] + b_hh[i];
}

// ---------------------------------------------------------------------------
// Fused MFMA LSTM. Block = 8 batch rows, 512 threads (8 waves), grid 512
// (2 blocks/CU, 4 waves/SIMD for cross-block phase overlap).
// Wave w owns gate tiles 2w,2w+1 (gates [32w,32w+32)); bf16 W in VGPRs.
//
// MFMA 16x16x32 lane mapping (verified round 2):
//   A: lane l supplies A[m=l&15][k=(l>>4)*8+j]
//   B: lane l supplies B[k=(l>>4)*8+j][n=l&15]
//   D: lane l reg q = D[m=(l>>4)*4+q][n=l&15]
//
// LDS A-fragments stored in lane order per 32-k slice (8 rows real):
//   addr = kc*512B + ((row&7)*4 + fk8_idx)*16B   -> read: abase + kc*512,
// lanes with row>=8 alias row-8 (broadcast, free); their D rows are masked.
// ---------------------------------------------------------------------------
__global__ __launch_bounds__(THREADS, 4)
void lstm_mfma8(const int* __restrict__ x,
                const float* __restrict__ emb,
                const short* __restrict__ wih_b,
                const short* __restrict__ whh_b,
                const float* __restrict__ bias_f,
                float* __restrict__ out) {
    __shared__ __align__(16) short s_emb[8 * 256];   // 8 slices * 512B = 4 KB
    __shared__ __align__(16) short s_h[2 * 256];     // 2 slices * 512B = 1 KB
    __shared__ float s_G[8 * 260];                   // padded stride 260
    __shared__ int s_idx[T_ * 8];                    // [t][row]

    const int tid  = threadIdx.x;
    const int lane = tid & 63;
    const int wave = tid >> 6;
    const int r0   = blockIdx.x * 8;

    // ---- init: indices (transposed [t][row]), zero h ----
    {
        int i = tid;   // i = row*64 + t, rows 0..7
        s_idx[(i & 63) * 8 + (i >> 6)] = x[r0 * T_ + i];
    }
    if (tid < 128) ((f32x4*)s_h)[tid] = (f32x4){0.f, 0.f, 0.f, 0.f};  // 2 KB? no: 128*16B = 2KB -> s_h is 1KB
    // (careful: s_h is 512 shorts = 1 KB = 64 float4s)
    // fix: only first 64 threads
    // (kept simple below)
    __syncthreads();
    if (tid < 64) ((f32x4*)s_h)[tid] = (f32x4){0.f, 0.f, 0.f, 0.f};

    // ---- weight fragments (register resident) ----
    const int fcol = lane & 15;
    const int fk8  = (lane >> 4) << 3;          // 0,8,16,24
    bf16x8 wIH[2][8], wHH[2][2];
    float biasv[2];
    #pragma unroll
    for (int i = 0; i < 2; ++i) {
        const int g = wave * 32 + i * 16 + fcol;
        const short* p = wih_b + g * E_ + fk8;
        #pragma unroll
        for (int kc = 0; kc < 8; ++kc) wIH[i][kc] = *(const bf16x8*)(p + kc * 32);
        const short* q = whh_b + g * H_ + fk8;
        #pragma unroll
        for (int kc = 0; kc < 2; ++kc) wHH[i][kc] = *(const bf16x8*)(q + kc * 32);
        biasv[i] = bias_f[g];
    }

    // ---- staging mapping: thread -> 8B half-fragment ----
    const int sf    = tid >> 1;                 // fragment 0..255
    const int skc   = sf >> 5;                  // k-chunk 0..7
    const int srow  = sf & 7;                   // batch row 0..7
    const int sfk   = (sf >> 3) & 3;            // k-sub 0..3
    const int shalf = tid & 1;
    short* s_wr = s_emb + skc * 256 + (srow * 4 + sfk) * 8 + shalf * 4;  // shorts
    const int sk0 = skc * 32 + sfk * 8 + shalf * 4;                      // emb col

    // ---- MFMA read bases (immediate-offset addressing) ----
    const short* a_rd = s_emb + ((fcol & 7) * 4 + (lane >> 4)) * 8;
    const short* h_rd = s_h  + ((fcol & 7) * 4 + (lane >> 4)) * 8;

    // ---- gate mapping: 1 row x 1 col per thread ----
    const int gr = wave;      // row 0..7
    const int gj = lane;      // col 0..63
    const float* gbase = s_G + gr * 260 + gj;
    short* h_wr = s_h + (gj >> 5) * 256 + (gr * 4 + ((gj >> 3) & 3)) * 8 + (gj & 7);
    float c_st = 0.0f;

    __syncthreads();

    // prefetch t=0 embedding (f32, converted at stage time)
    int ridx = s_idx[srow];
    float4 pf = *(const float4*)(emb + (size_t)ridx * E_ + sk0);

    for (int t = 0; t < T_; ++t) {
        // ---- stage: convert prefetched f32 -> bf16, linear 8B write ----
        {
            bf16x4 w4;
            w4[0] = f2bf(pf.x); w4[1] = f2bf(pf.y);
            w4[2] = f2bf(pf.z); w4[3] = f2bf(pf.w);
            *(bf16x4*)s_wr = w4;
        }
        __syncthreads();   // B1: emb(t) staged, h(t-1) visible

        // ---- prefetch t+1 (hidden under MFMA + gate phases) ----
        if (t + 1 < T_) {
            int ri = s_idx[(t + 1) * 8 + srow];
            pf = *(const float4*)(emb + (size_t)ri * E_ + sk0);
        }

        // ---- MFMA: G = emb*Wih + h*Whh + bias (20 MFMA/wave) ----
        f32x4 a0 = {biasv[0], biasv[0], biasv[0], biasv[0]};
        f32x4 a1 = {biasv[1], biasv[1], biasv[1], biasv[1]};
        #pragma unroll
        for (int kc = 0; kc < 8; ++kc) {
            bf16x8 av = *(const bf16x8*)(a_rd + kc * 256);
            a0 = __builtin_amdgcn_mfma_f32_16x16x32_bf16(av, wIH[0][kc], a0, 0, 0, 0);
            a1 = __builtin_amdgcn_mfma_f32_16x16x32_bf16(av, wIH[1][kc], a1, 0, 0, 0);
        }
        #pragma unroll
        for (int kc = 0; kc < 2; ++kc) {
            bf16x8 hv = *(const bf16x8*)(h_rd + kc * 256);
            a0 = __builtin_amdgcn_mfma_f32_16x16x32_bf16(hv, wHH[0][kc], a0, 0, 0, 0);
            a1 = __builtin_amdgcn_mfma_f32_16x16x32_bf16(hv, wHH[1][kc], a1, 0, 0, 0);
        }

        // ---- write G rows 0..7 (lanes with D-row < 8) ----
        if ((lane >> 4) < 2) {
            float* gw = s_G + ((lane >> 4) * 4) * 260 + wave * 32 + fcol;
            #pragma unroll
            for (int q = 0; q < 4; ++q) {
                gw[q * 260]      = a0[q];
                gw[q * 260 + 16] = a1[q];
            }
        }
        __syncthreads();   // B2: G complete, emb reads done (safe to restage)

        // ---- gate math: 1 (row,col) per thread ----
        float gi = gbase[0], gf = gbase[64], gg = gbase[128], go = gbase[192];
        c_st = sigm(gf) * c_st + sigm(gi) * tanh_(gg);
        float hval = sigm(go) * tanh_(c_st);
        *h_wr = f2bf(hval);

        if (t == T_ - 1) out[(r0 + gr) * H_ + gj] = hval;
    }
}

// ---------------------------------------------------------------------------
extern "C" void kernel_launch(void* const* d_in, const int* in_sizes, int n_in,
                              void* d_out, int out_size, void* d_ws, size_t ws_size,
                              hipStream_t stream) {
    const int*   x         = (const int*)d_in[0];
    const float* emb_table = (const float*)d_in[1];
    const float* W_ih      = (const float*)d_in[2];
    const float* W_hh      = (const float*)d_in[3];
    const float* b_ih      = (const float*)d_in[4];
    const float* b_hh      = (const float*)d_in[5];
    float*       out       = (float*)d_out;

    short* wih_b  = (short*)d_ws;            // 65536 shorts (128 KB)
    short* whh_b  = wih_b + 65536;           // 16384 shorts (32 KB)
    float* bias_f = (float*)(whh_b + 16384); // 256 floats (1 KB)

    prep_kernel<<<64, 256, 0, stream>>>(W_ih, W_hh, b_ih, b_hh,
                                        wih_b, whh_b, bias_f);
    lstm_mfma8<<<B_ / 8, THREADS, 0, stream>>>(x, emb_table,
                                               wih_b, whh_b, bias_f, out);
}

// Round 4
// 88.216 us; speedup vs baseline: 14.2264x; 1.2743x over previous
//
#include <hip/hip_runtime.h>
#include <math.h>

#define B_ 4096
#define T_ 64
#define E_ 256
#define H_ 64
#define THREADS 1024
#define BB 16

typedef __attribute__((ext_vector_type(8))) short bf16x8;
typedef __attribute__((ext_vector_type(4))) short bf16x4;
typedef __attribute__((ext_vector_type(4))) float f32x4;

__device__ __forceinline__ short f2bf(float x) {
    // round-to-nearest-even f32 -> bf16
    unsigned u = __float_as_uint(x);
    return (short)((u + 0x7FFFu + ((u >> 16) & 1u)) >> 16);
}
__device__ __forceinline__ float sigm(float x) { return 1.0f / (1.0f + __expf(-x)); }
__device__ __forceinline__ float tanh_(float x) { return 1.0f - 2.0f / (1.0f + __expf(2.0f * x)); }

// ---------------------------------------------------------------------------
// Prep:
//  wih_frag: W_ih as per-wave MFMA B-fragments with INTERLEAVED gate columns.
//    flat idx = ((v*2+tile)*8 + kc)*512 + lane*8 + jj
//    tile col n = lane&15 -> gate g = tile*128 + (n&1)*64 + v*8 + (n>>1)
//    k = kc*32 + (lane>>4)*8 + jj
//  whh_g: bf16 row-major [256][64] (copied to padded LDS by main kernel)
//  bias_f: fused bias
// ---------------------------------------------------------------------------
__global__ void prep_kernel(const float* __restrict__ W_ih,
                            const float* __restrict__ W_hh,
                            const float* __restrict__ b_ih,
                            const float* __restrict__ b_hh,
                            short* __restrict__ wih_frag,
                            short* __restrict__ whh_g,
                            float* __restrict__ bias_f) {
    int tid = blockIdx.x * blockDim.x + threadIdx.x;
    int stride = gridDim.x * blockDim.x;
    for (int i = tid; i < 65536; i += stride) {
        int jj = i & 7;
        int l  = (i >> 3) & 63;
        int kc = (i >> 9) & 7;
        int tl = (i >> 12) & 1;
        int v  = i >> 13;
        int u = (l & 15) >> 1, p = l & 1;
        int g = tl * 128 + p * 64 + v * 8 + u;
        int k = kc * 32 + (l >> 4) * 8 + jj;
        wih_frag[i] = f2bf(W_ih[g * E_ + k]);
    }
    for (int i = tid; i < 256 * 64; i += stride) whh_g[i] = f2bf(W_hh[i]);
    for (int i = tid; i < 256; i += stride) bias_f[i] = b_ih[i] + b_hh[i];
}

// ---------------------------------------------------------------------------
// Fused MFMA LSTM. grid 256 (1 block/CU), 1024 threads = 16 waves, BB=16.
//  waves 0-7: compute (2 interleaved gate tiles each, W_ih in VGPRs,
//             W_hh from padded LDS, in-register gate math via lane-pair shfl)
//  waves 8-15: stage emb(t+1) f32->bf16 into double-buffered LDS
// One __syncthreads per timestep.
//
// MFMA 16x16x32 lane mapping (verified R2/R3):
//   A: lane l -> A[m=l&15][k=(l>>4)*8+jj];  B: lane l -> B[k][n=l&15]
//   D: lane l reg q -> D[m=(l>>4)*4+q][n=l&15]
// LDS strides chosen so fragment reads are 2-way-max bank aliased (free):
//   emb stride 528B (132w = 4 mod 32), h / whh stride 144B (36w = 4 mod 32).
// ---------------------------------------------------------------------------
__global__ __launch_bounds__(THREADS, 4)
void lstm_mfma16(const int* __restrict__ x,
                 const float* __restrict__ emb,
                 const short* __restrict__ wih_frag,
                 const short* __restrict__ whh_g,
                 const float* __restrict__ bias_f,
                 float* __restrict__ out) {
    __shared__ __align__(16) short s_emb[2][BB][264];   // 16.5 KB dbuf
    __shared__ __align__(16) short s_hb[2][BB][72];     // 4.5 KB dbuf
    __shared__ __align__(16) short s_whh[256 * 72];     // 36 KB padded
    __shared__ int s_idx[T_][BB];                       // 4 KB

    const int tid  = threadIdx.x;
    const int lane = tid & 63;
    const int wave = tid >> 6;
    const int r0   = blockIdx.x * BB;

    // ---- init: token indices, zero h, copy whh to padded LDS ----
    {
        int row = tid >> 6;        // 0..15
        int t   = tid & 63;
        s_idx[t][row] = x[(r0 + row) * T_ + t];
    }
    for (int i = tid; i < 2 * BB * 72 / 2; i += THREADS) ((int*)s_hb)[i] = 0;
    {
        int g = tid >> 2, seg = (tid & 3) * 16;
        *(bf16x8*)(s_whh + g * 72 + seg)     = *(const bf16x8*)(whh_g + g * 64 + seg);
        *(bf16x8*)(s_whh + g * 72 + seg + 8) = *(const bf16x8*)(whh_g + g * 64 + seg + 8);
    }

    const int p  = lane & 1;
    const int c4 = lane >> 4;
    const int u  = (lane & 15) >> 1;

    // compute-wave state
    bf16x8 wA[8], wB[8];
    float bA = 0.f, bB = 0.f;
    int emb_base = 0, h_base = 0, whh_base = 0;
    float scl2 = 0.f, offB = 0.f;
    if (wave < 8) {
        const int v = wave;
        const short* wp = wih_frag + v * 8192 + lane * 8;
        #pragma unroll
        for (int kc = 0; kc < 8; ++kc) {
            wA[kc] = *(const bf16x8*)(wp + kc * 512);
            wB[kc] = *(const bf16x8*)(wp + 4096 + kc * 512);
        }
        const int gA = p * 64 + v * 8 + u;
        bA = bias_f[gA];
        bB = bias_f[128 + gA];
        emb_base = (lane & 15) * 528 + c4 * 16;
        h_base   = (lane & 15) * 144 + c4 * 16;
        whh_base = gA * 144 + c4 * 16;
        scl2 = p ? 1.0f : 2.0f;    // sigmoid arg scale (tanh(x)=2*sigm(2x)-1)
        offB = p ? 0.0f : -1.0f;
    }

    // stage-wave mapping: wave s owns rows 2s,2s+1; lane -> 4-elem col chunk
    const int srow = ((wave - 8) * 2 + (lane >> 5)) & 15;
    const int scb  = (lane & 31) * 4;

    __syncthreads();   // s_idx visible

    // ---- prologue: stage emb(0) into buf 0 ----
    if (wave >= 8) {
        int tok = s_idx[0][srow];
        const float* p0 = emb + (size_t)tok * E_ + scb;
        float4 f0 = *(const float4*)p0;
        float4 f1 = *(const float4*)(p0 + 128);
        bf16x4 w0, w1;
        w0[0] = f2bf(f0.x); w0[1] = f2bf(f0.y); w0[2] = f2bf(f0.z); w0[3] = f2bf(f0.w);
        w1[0] = f2bf(f1.x); w1[1] = f2bf(f1.y); w1[2] = f2bf(f1.z); w1[3] = f2bf(f1.w);
        short* dst = &s_emb[0][srow][0] + scb;
        *(bf16x4*)dst         = w0;
        *(bf16x4*)(dst + 128) = w1;
    }
    __syncthreads();   // buf0 + h0 + whh ready

    float c0 = 0.f, c1 = 0.f;   // cell state: rows m0, m0+1

    for (int t = 0; t < T_; ++t) {
        if (wave < 8) {
            const char* eb = (const char*)&s_emb[t & 1][0][0] + emb_base;
            const char* hb = (const char*)&s_hb[t & 1][0][0] + h_base;
            f32x4 accA = {bA, bA, bA, bA};
            f32x4 accB = {bB, bB, bB, bB};
            #pragma unroll
            for (int kc = 0; kc < 8; ++kc) {
                bf16x8 av = *(const bf16x8*)(eb + kc * 64);
                accA = __builtin_amdgcn_mfma_f32_16x16x32_bf16(av, wA[kc], accA, 0, 0, 0);
                accB = __builtin_amdgcn_mfma_f32_16x16x32_bf16(av, wB[kc], accB, 0, 0, 0);
            }
            const char* wh = (const char*)s_whh + whh_base;
            #pragma unroll
            for (int kc = 0; kc < 2; ++kc) {
                bf16x8 hv = *(const bf16x8*)(hb + kc * 64);
                bf16x8 qa = *(const bf16x8*)(wh + kc * 64);
                bf16x8 qb = *(const bf16x8*)(wh + 18432 + kc * 64);
                accA = __builtin_amdgcn_mfma_f32_16x16x32_bf16(hv, qa, accA, 0, 0, 0);
                accB = __builtin_amdgcn_mfma_f32_16x16x32_bf16(hv, qb, accB, 0, 0, 0);
            }

            // ---- in-register gates ----
            // even lane (p=0): accA=i-pre, accB=g-pre ; odd: accA=f-pre, accB=o-pre
            float sA[4], Bv[4];
            #pragma unroll
            for (int q = 0; q < 4; ++q) {
                sA[q] = sigm(accA[q]);                    // sigm(i) | sigm(f)
                float uq = sigm(scl2 * accB[q]);
                Bv[q] = uq * scl2 + offB;                 // tanh(g) | sigm(o)
            }
            // lane-pair exchange (partner = lane^1, same col j, same q-rows)
            float s1 = p ? sA[0] : sA[2] * Bv[2];
            float r1 = __shfl_xor(s1, 1);                 // even<-SF0 ; odd<-A2
            float s2 = p ? sA[1] : sA[3] * Bv[3];
            float r2 = __shfl_xor(s2, 1);                 // even<-SF1 ; odd<-A3
            float r3 = __shfl_xor(Bv[0], 1);              // even<-SO0
            float r4 = __shfl_xor(Bv[1], 1);              // even<-SO1

            float fc0 = p ? sA[2] : r1;
            float ic0 = p ? r1 : sA[0] * Bv[0];
            float oc0 = p ? Bv[2] : r3;
            float fc1 = p ? sA[3] : r2;
            float ic1 = p ? r2 : sA[1] * Bv[1];
            float oc1 = p ? Bv[3] : r4;
            c0 = fc0 * c0 + ic0;
            c1 = fc1 * c1 + ic1;
            float h0 = oc0 * tanh_(c0);
            float h1 = oc1 * tanh_(c1);

            const int m0 = c4 * 4 + p * 2;      // rows m0, m0+1
            const int j  = wave * 8 + u;        // h column
            short* hw = &s_hb[(t + 1) & 1][0][0] + m0 * 72 + j;
            hw[0]  = f2bf(h0);
            hw[72] = f2bf(h1);
            if (t == T_ - 1) {
                out[(r0 + m0) * H_ + j]     = h0;
                out[(r0 + m0 + 1) * H_ + j] = h1;
            }
        } else if (t + 1 < T_) {
            // ---- stage emb(t+1) into buf (t+1)&1 ----
            int tok = s_idx[t + 1][srow];
            const float* p0 = emb + (size_t)tok * E_ + scb;
            float4 f0 = *(const float4*)p0;
            float4 f1 = *(const float4*)(p0 + 128);
            bf16x4 w0, w1;
            w0[0] = f2bf(f0.x); w0[1] = f2bf(f0.y); w0[2] = f2bf(f0.z); w0[3] = f2bf(f0.w);
            w1[0] = f2bf(f1.x); w1[1] = f2bf(f1.y); w1[2] = f2bf(f1.z); w1[3] = f2bf(f1.w);
            short* dst = &s_emb[(t + 1) & 1][srow][0] + scb;
            *(bf16x4*)dst         = w0;
            *(bf16x4*)(dst + 128) = w1;
        }
        __syncthreads();
    }
}

// ---------------------------------------------------------------------------
extern "C" void kernel_launch(void* const* d_in, const int* in_sizes, int n_in,
                              void* d_out, int out_size, void* d_ws, size_t ws_size,
                              hipStream_t stream) {
    const int*   x         = (const int*)d_in[0];
    const float* emb_table = (const float*)d_in[1];
    const float* W_ih      = (const float*)d_in[2];
    const float* W_hh      = (const float*)d_in[3];
    const float* b_ih      = (const float*)d_in[4];
    const float* b_hh      = (const float*)d_in[5];
    float*       out       = (float*)d_out;

    short* wih_frag = (short*)d_ws;               // 65536 shorts (128 KB)
    short* whh_g    = wih_frag + 65536;           // 16384 shorts (32 KB)
    float* bias_f   = (float*)(whh_g + 16384);    // 256 floats (1 KB)

    prep_kernel<<<64, 256, 0, stream>>>(W_ih, W_hh, b_ih, b_hh,
                                        wih_frag, whh_g, bias_f);
    lstm_mfma16<<<B_ / BB, THREADS, 0, stream>>>(x, emb_table,
                                                 wih_frag, whh_g, bias_f, out);
}